// Round 8
// baseline (1246.769 us; speedup 1.0000x reference)
//
#include <hip/hip_runtime.h>
#include <hip/hip_bf16.h>

#define BATCH 4096
#define TSTEPS 256
#define NF 5
#define H 64
#define BT 4           // batch tile per block; batch b at sparse row 4b
#define LDH 136        // hreg row stride in ushorts (272B, 4-bank stride)
#define NBLK (BATCH / BT)   // 1024 blocks -> 4 blocks/CU -> 4 waves/SIMD

typedef __attribute__((ext_vector_type(8))) short bf16x8;
typedef __attribute__((ext_vector_type(4))) float f32x4;

#define LOG2E 1.4426950408889634f
#define TWOLOG2E 2.8853900817779268f

__device__ __forceinline__ ushort f2bf(float f) {
    union { float f; unsigned u; } v; v.f = f;
    unsigned u = v.u;
    unsigned r = (u + 0x7FFFu + ((u >> 16) & 1u)) >> 16;  // RNE
    return (ushort)r;
}
__device__ __forceinline__ float bf2f(ushort s) {
    union { unsigned u; float f; } v; v.u = ((unsigned)s) << 16;
    return v.f;
}
// pack two fp32 -> two bf16 (RNE) in one instruction
__device__ __forceinline__ unsigned pk_bf16(float lo, float hi) {
    unsigned pk;
    asm("v_cvt_pk_bf16_f32 %0, %1, %2" : "=v"(pk) : "v"(lo), "v"(hi));
    return pk;
}

__global__ __launch_bounds__(256, 4)
void lstm2_kernel(const float* __restrict__ x,
                  const float* __restrict__ Wih0, const float* __restrict__ Whh0,
                  const float* __restrict__ bih0, const float* __restrict__ bhh0,
                  const float* __restrict__ Wih1, const float* __restrict__ Whh1,
                  const float* __restrict__ bih1, const float* __restrict__ bhh1,
                  const float* __restrict__ Wfc, const float* __restrict__ bfc,
                  float* __restrict__ out)
{
    __shared__ union {
        ushort xs[TSTEPS * BT * 8];   // bf16 x [t][b][8]; cols 5,6 = 1.0 (bias), 7 = 0
        float  hfin[BT * H];          // epilogue: fp32 final h1
    } uS;
    __shared__ ushort hreg[2][16 * LDH];  // dbuf state; cols 0..63 h0, 64..127 h1

    const int tid = threadIdx.x;
    const int w   = tid >> 6;    // wave 0..3
    const int l   = tid & 63;
    const int g   = l >> 4;      // k-group; also owns batch g in EW
    const int lr  = l & 15;      // A row / B,D col index
    const int bb  = blockIdx.x * BT;

    // ---- stage x tile into LDS as bf16; pad cols 5,6 = 1.0 (bias cols) ----
    {
        const int b  = tid & 3;
        const int t0 = tid >> 2;
        const ushort one = f2bf(1.0f);
        for (int tt = t0; tt < TSTEPS; tt += 64) {
            const float* xp = x + ((size_t)(bb + b) * TSTEPS + tt) * NF;
            bf16x8 v;
            v[0] = (short)f2bf(xp[0]); v[1] = (short)f2bf(xp[1]);
            v[2] = (short)f2bf(xp[2]); v[3] = (short)f2bf(xp[3]);
            v[4] = (short)f2bf(xp[4]); v[5] = (short)one; v[6] = (short)one; v[7] = 0;
            *(bf16x8*)&uS.xs[(tt * BT + b) * 8] = v;
        }
    }
    for (int i = tid; i < 2 * 16 * LDH; i += 256) hreg[0][i] = 0;

    // ---- weight fragments resident in VGPRs, gate-scaled for fused EW ----
    // gates i,f,o scaled +log2e; gate g scaled +2log2e.
    // wave w covers unit u = 16w+lr; gate gi at col n = 64*gi + u.
    // k-map (A and B): chunk c, group g, elem j -> k = 32c + 8g + j.
    const int u = 16 * w + lr;
    bf16x8 w0f[4][3], w1f[4][4];
    float b1v[4];                       // L1 bias as scalars (added in EW)
    #pragma unroll
    for (int gi = 0; gi < 4; ++gi) {
        const float sc = (gi == 2) ? TWOLOG2E : LOG2E;
        const int n = 64 * gi + u;
        const float b0 = (bih0[n] + bhh0[n]) * sc;
        b1v[gi] = (bih1[n] + bhh1[n]) * sc;
        #pragma unroll
        for (int c = 0; c < 2; ++c) {                  // layer0 recurrent
            const float* p = Whh0 + n * H + 32 * c + 8 * g;
            bf16x8 v;
            #pragma unroll
            for (int j = 0; j < 8; ++j) v[j] = (short)f2bf(p[j] * sc);
            w0f[gi][c] = v;
        }
        {   // layer0 x-chunk: cols 0..4 Wih0 scaled; col5 bias_hi, col6 bias_lo
            const ushort bhi = f2bf(b0);
            const ushort blo = f2bf(b0 - bf2f(bhi));
            bf16x8 v;
            #pragma unroll
            for (int j = 0; j < 8; ++j) {
                int kk = 8 * g + j;
                ushort val = 0;
                if (kk < NF) val = f2bf(Wih0[n * NF + kk] * sc);
                else if (kk == 5) val = bhi;
                else if (kk == 6) val = blo;
                v[j] = (short)val;
            }
            w0f[gi][2] = v;
        }
        #pragma unroll
        for (int c = 0; c < 4; ++c) {                  // layer1: [Wih1 | Whh1]
            const float* p = (c < 2) ? (Wih1 + n * H + 32 * c + 8 * g)
                                     : (Whh1 + n * H + 32 * (c - 2) + 8 * g);
            bf16x8 v;
            #pragma unroll
            for (int j = 0; j < 8; ++j) v[j] = (short)f2bf(p[j] * sc);
            w1f[gi][c] = v;
        }
    }

    // fused LSTM cell: 5 exp2 + 2 rcp.
    //   c' = [e_f (e_i+1)(E_g+1) c + (e_f+1) e_i (E_g-1)] / [(e_f+1)(e_i+1)(E_g+1)]
    //   h  = e_o (E_c-1) / [(e_o+1)(E_c+1)],  E_c = exp2(clamp(2c'·log2e, ±15))
    auto cellfuse = [&](float xi, float xf, float xg, float xo, float& cst) -> float {
        float ei = __builtin_amdgcn_exp2f(xi);
        float ef = __builtin_amdgcn_exp2f(xf);
        float Eg = __builtin_amdgcn_exp2f(xg);
        float eo = __builtin_amdgcn_exp2f(xo);
        float a1 = ei + 1.0f, a2 = ef + 1.0f, a3 = Eg + 1.0f, a4 = Eg - 1.0f;
        float P  = a1 * a3;
        float t1 = ef * cst;
        float t3 = (a2 * ei) * a4;
        float num = fmaf(t1, P, t3);
        float R  = __builtin_amdgcn_rcpf(P * a2);
        float cn = num * R;
        cst = cn;
        float ct = __builtin_amdgcn_fmed3f(cn * TWOLOG2E, -15.0f, 15.0f);
        float Ec = __builtin_amdgcn_exp2f(ct);
        return (eo * (Ec - 1.0f)) * __builtin_amdgcn_rcpf((eo + 1.0f) * (Ec + 1.0f));
    };

    // lane (g,lr): owns batch g (D row 4g, reg 0), unit u = 16w+lr
    float c0 = 0.0f, c1 = 0.0f, h1fin = 0.0f;
    const bool xlane = (g == 0) && ((lr & 3) == 0);
    const int  bx    = lr >> 2;        // batch at A-row lr (valid when lr%4==0)

    __syncthreads();

    const int arow = lr * LDH;
    const f32x4 kZ = {0, 0, 0, 0};

    // Pipelined: iteration t = layer0 step t (h0[t-1], x[t]) + layer1 step t-1.
    // Double-buffered hreg -> ONE barrier per iteration.
    auto body = [&](int t, const ushort* __restrict__ rb, ushort* __restrict__ wb) {
        const bool do0 = (t < TSTEPS);
        const bool do1 = (t >= 1);

        bf16x8 a00 = *(const bf16x8*)&rb[arow + 8 * g];        // h0 chunk 0
        bf16x8 a01 = *(const bf16x8*)&rb[arow + 32 + 8 * g];   // h0 chunk 1
        bf16x8 a12, a13;
        if (do1) {
            a12 = *(const bf16x8*)&rb[arow + 64 + 8 * g];      // h1 chunk 0
            a13 = *(const bf16x8*)&rb[arow + 96 + 8 * g];      // h1 chunk 1
        }
        bf16x8 ax = {0, 0, 0, 0, 0, 0, 0, 0};
        if (do0 && xlane) ax = *(const bf16x8*)&uS.xs[(t * BT + bx) * 8];

        f32x4 acc0[4], acc1[4];
        if (do0) {
            #pragma unroll
            for (int gi = 0; gi < 4; ++gi) acc0[gi] = __builtin_amdgcn_mfma_f32_16x16x32_bf16(a00, w0f[gi][0], kZ, 0, 0, 0);
            #pragma unroll
            for (int gi = 0; gi < 4; ++gi) acc0[gi] = __builtin_amdgcn_mfma_f32_16x16x32_bf16(a01, w0f[gi][1], acc0[gi], 0, 0, 0);
            #pragma unroll
            for (int gi = 0; gi < 4; ++gi) acc0[gi] = __builtin_amdgcn_mfma_f32_16x16x32_bf16(ax,  w0f[gi][2], acc0[gi], 0, 0, 0);
        }
        if (do1) {
            #pragma unroll
            for (int gi = 0; gi < 4; ++gi) acc1[gi] = __builtin_amdgcn_mfma_f32_16x16x32_bf16(a00, w1f[gi][0], kZ, 0, 0, 0);
            #pragma unroll
            for (int gi = 0; gi < 4; ++gi) acc1[gi] = __builtin_amdgcn_mfma_f32_16x16x32_bf16(a01, w1f[gi][1], acc1[gi], 0, 0, 0);
            #pragma unroll
            for (int gi = 0; gi < 4; ++gi) acc1[gi] = __builtin_amdgcn_mfma_f32_16x16x32_bf16(a12, w1f[gi][2], acc1[gi], 0, 0, 0);
            #pragma unroll
            for (int gi = 0; gi < 4; ++gi) acc1[gi] = __builtin_amdgcn_mfma_f32_16x16x32_bf16(a13, w1f[gi][3], acc1[gi], 0, 0, 0);
        }

        float h0v = 0.0f, h1v = 0.0f;
        if (do0) h0v = cellfuse(acc0[0][0], acc0[1][0], acc0[2][0], acc0[3][0], c0);
        if (do1) {
            h1v = cellfuse(acc1[0][0] + b1v[0], acc1[1][0] + b1v[1],
                           acc1[2][0] + b1v[2], acc1[3][0] + b1v[3], c1);
            h1fin = h1v;
        }
        unsigned pk = pk_bf16(h0v, h1v);
        if (do0) wb[(4 * g) * LDH + u]      = (ushort)pk;
        if (do1) wb[(4 * g) * LDH + 64 + u] = (ushort)(pk >> 16);
        __syncthreads();
    };

    #pragma unroll 1
    for (int t = 0; t < TSTEPS; t += 2) {
        body(t,     hreg[0], hreg[1]);
        body(t + 1, hreg[1], hreg[0]);
    }
    body(TSTEPS, hreg[0], hreg[1]);   // drain: layer1 step T-1

    // epilogue: FC on fp32 final h1
    uS.hfin[g * H + u] = h1fin;
    __syncthreads();
    if (tid < BT * 2) {
        const int b = tid >> 1, cls = tid & 1;
        float s = bfc[cls];
        for (int k = 0; k < H; ++k) s += uS.hfin[b * H + k] * Wfc[cls * H + k];
        out[(size_t)(bb + b) * 2 + cls] = s;
    }
}

extern "C" void kernel_launch(void* const* d_in, const int* in_sizes, int n_in,
                              void* d_out, int out_size, void* d_ws, size_t ws_size,
                              hipStream_t stream) {
    const float* x    = (const float*)d_in[0];
    const float* Wih0 = (const float*)d_in[1];
    const float* Whh0 = (const float*)d_in[2];
    const float* bih0 = (const float*)d_in[3];
    const float* bhh0 = (const float*)d_in[4];
    const float* Wih1 = (const float*)d_in[5];
    const float* Whh1 = (const float*)d_in[6];
    const float* bih1 = (const float*)d_in[7];
    const float* bhh1 = (const float*)d_in[8];
    const float* Wfc  = (const float*)d_in[9];
    const float* bfc  = (const float*)d_in[10];
    float* out = (float*)d_out;

    lstm2_kernel<<<NBLK, 256, 0, stream>>>(x, Wih0, Whh0, bih0, bhh0,
                                           Wih1, Whh1, bih1, bhh1, Wfc, bfc, out);
}

// Round 9
// 321.631 us; speedup vs baseline: 3.8764x; 3.8764x over previous
//
#include <hip/hip_runtime.h>
#include <hip/hip_bf16.h>

#define BATCH 4096
#define TSTEPS 256
#define NF 5
#define H 64
#define BT 4           // batch tile per block; batch b at sparse row 4b
#define LDH 136        // hreg row stride in ushorts (272B)
#define NBLK (BATCH / BT)   // 1024 blocks -> 4 blocks/CU -> 4 waves/SIMD

typedef __attribute__((ext_vector_type(8))) short bf16x8;
typedef __attribute__((ext_vector_type(4))) float f32x4;

#define LOG2E 1.4426950408889634f
#define TWOLOG2E 2.8853900817779268f

__device__ __forceinline__ ushort f2bf(float f) {
    union { float f; unsigned u; } v; v.f = f;
    unsigned u = v.u;
    unsigned r = (u + 0x7FFFu + ((u >> 16) & 1u)) >> 16;  // RNE
    return (ushort)r;
}
__device__ __forceinline__ float bf2f(ushort s) {
    union { unsigned u; float f; } v; v.u = ((unsigned)s) << 16;
    return v.f;
}
// pack two fp32 -> two bf16 (RNE) in one instruction
__device__ __forceinline__ unsigned pk_bf16(float lo, float hi) {
    unsigned pk;
    asm("v_cvt_pk_bf16_f32 %0, %1, %2" : "=v"(pk) : "v"(lo), "v"(hi));
    return pk;
}

// NOTE: launch_bounds(256,2) keeps the compiler's VGPR budget at 256 (no spills;
// measured natural usage ~128). Actual residency comes from resources: 128 VGPR
// -> 4 waves/SIMD, LDS 25KB*4 = 100KB < 160KB -> 4 blocks/CU with the 1024-block grid.
__global__ __launch_bounds__(256, 2)
void lstm2_kernel(const float* __restrict__ x,
                  const float* __restrict__ Wih0, const float* __restrict__ Whh0,
                  const float* __restrict__ bih0, const float* __restrict__ bhh0,
                  const float* __restrict__ Wih1, const float* __restrict__ Whh1,
                  const float* __restrict__ bih1, const float* __restrict__ bhh1,
                  const float* __restrict__ Wfc, const float* __restrict__ bfc,
                  float* __restrict__ out)
{
    __shared__ union {
        ushort xs[TSTEPS * BT * 8];   // bf16 x [t][b][8]; cols 5,6 = 1.0 (bias), 7 = 0
        float  hfin[BT * H];          // epilogue: fp32 final h1
    } uS;
    __shared__ ushort hreg[2][16 * LDH];  // dbuf state; cols 0..63 h0, 64..127 h1

    const int tid = threadIdx.x;
    const int w   = tid >> 6;    // wave 0..3
    const int l   = tid & 63;
    const int g   = l >> 4;      // k-group; also owns batch g in EW
    const int lr  = l & 15;      // A row / B,D col index
    const int bb  = blockIdx.x * BT;

    // ---- stage x tile into LDS as bf16; pad cols 5,6 = 1.0 (bias cols) ----
    {
        const int b  = tid & 3;
        const int t0 = tid >> 2;
        const ushort one = f2bf(1.0f);
        for (int tt = t0; tt < TSTEPS; tt += 64) {
            const float* xp = x + ((size_t)(bb + b) * TSTEPS + tt) * NF;
            bf16x8 v;
            v[0] = (short)f2bf(xp[0]); v[1] = (short)f2bf(xp[1]);
            v[2] = (short)f2bf(xp[2]); v[3] = (short)f2bf(xp[3]);
            v[4] = (short)f2bf(xp[4]); v[5] = (short)one; v[6] = (short)one; v[7] = 0;
            *(bf16x8*)&uS.xs[(tt * BT + b) * 8] = v;
        }
    }
    for (int i = tid; i < 2 * 16 * LDH; i += 256) hreg[0][i] = 0;

    // ---- weight fragments resident in VGPRs, gate-scaled for fused EW ----
    // gates i,f,o scaled +log2e; gate g scaled +2log2e.
    // wave w covers unit u = 16w+lr; gate gi at col n = 64*gi + u.
    // k-map (A and B): chunk c, group g, elem j -> k = 32c + 8g + j.
    const int u = 16 * w + lr;
    bf16x8 w0f[4][3], w1f[4][4];
    float b1v[4];                       // L1 bias as scalars (added in EW)
    #pragma unroll
    for (int gi = 0; gi < 4; ++gi) {
        const float sc = (gi == 2) ? TWOLOG2E : LOG2E;
        const int n = 64 * gi + u;
        const float b0 = (bih0[n] + bhh0[n]) * sc;
        b1v[gi] = (bih1[n] + bhh1[n]) * sc;
        #pragma unroll
        for (int c = 0; c < 2; ++c) {                  // layer0 recurrent
            const float* p = Whh0 + n * H + 32 * c + 8 * g;
            bf16x8 v;
            #pragma unroll
            for (int j = 0; j < 8; ++j) v[j] = (short)f2bf(p[j] * sc);
            w0f[gi][c] = v;
        }
        {   // layer0 x-chunk: cols 0..4 Wih0 scaled; col5 bias_hi, col6 bias_lo
            const ushort bhi = f2bf(b0);
            const ushort blo = f2bf(b0 - bf2f(bhi));
            bf16x8 v;
            #pragma unroll
            for (int j = 0; j < 8; ++j) {
                int kk = 8 * g + j;
                ushort val = 0;
                if (kk < NF) val = f2bf(Wih0[n * NF + kk] * sc);
                else if (kk == 5) val = bhi;
                else if (kk == 6) val = blo;
                v[j] = (short)val;
            }
            w0f[gi][2] = v;
        }
        #pragma unroll
        for (int c = 0; c < 4; ++c) {                  // layer1: [Wih1 | Whh1]
            const float* p = (c < 2) ? (Wih1 + n * H + 32 * c + 8 * g)
                                     : (Whh1 + n * H + 32 * (c - 2) + 8 * g);
            bf16x8 v;
            #pragma unroll
            for (int j = 0; j < 8; ++j) v[j] = (short)f2bf(p[j] * sc);
            w1f[gi][c] = v;
        }
    }

    // fused LSTM cell: 5 exp2 + 2 rcp.
    //   c' = [e_f (e_i+1)(E_g+1) c + (e_f+1) e_i (E_g-1)] / [(e_f+1)(e_i+1)(E_g+1)]
    //   h  = e_o (E_c-1) / [(e_o+1)(E_c+1)],  E_c = exp2(clamp(2c'·log2e, ±15))
    auto cellfuse = [&](float xi, float xf, float xg, float xo, float& cst) -> float {
        float ei = __builtin_amdgcn_exp2f(xi);
        float ef = __builtin_amdgcn_exp2f(xf);
        float Eg = __builtin_amdgcn_exp2f(xg);
        float eo = __builtin_amdgcn_exp2f(xo);
        float a1 = ei + 1.0f, a2 = ef + 1.0f, a3 = Eg + 1.0f, a4 = Eg - 1.0f;
        float P  = a1 * a3;
        float t1 = ef * cst;
        float t3 = (a2 * ei) * a4;
        float num = fmaf(t1, P, t3);
        float R  = __builtin_amdgcn_rcpf(P * a2);
        float cn = num * R;
        cst = cn;
        float ct = __builtin_amdgcn_fmed3f(cn * TWOLOG2E, -15.0f, 15.0f);
        float Ec = __builtin_amdgcn_exp2f(ct);
        return (eo * (Ec - 1.0f)) * __builtin_amdgcn_rcpf((eo + 1.0f) * (Ec + 1.0f));
    };

    // lane (g,lr): owns batch g (D row 4g, reg 0), unit u = 16w+lr
    float c0 = 0.0f, c1 = 0.0f, h1fin = 0.0f;
    const bool xlane = (g == 0) && ((lr & 3) == 0);
    const int  bx    = lr >> 2;        // batch at A-row lr (valid when lr%4==0)

    __syncthreads();

    const int arow = lr * LDH;
    const f32x4 kZ = {0, 0, 0, 0};

    // Pipelined: iteration t = layer0 step t (h0[t-1], x[t]) + layer1 step t-1.
    // Double-buffered hreg -> ONE barrier per iteration.
    auto body = [&](int t, const ushort* __restrict__ rb, ushort* __restrict__ wb) {
        const bool do0 = (t < TSTEPS);
        const bool do1 = (t >= 1);

        bf16x8 a00 = *(const bf16x8*)&rb[arow + 8 * g];        // h0 chunk 0
        bf16x8 a01 = *(const bf16x8*)&rb[arow + 32 + 8 * g];   // h0 chunk 1
        bf16x8 a12, a13;
        if (do1) {
            a12 = *(const bf16x8*)&rb[arow + 64 + 8 * g];      // h1 chunk 0
            a13 = *(const bf16x8*)&rb[arow + 96 + 8 * g];      // h1 chunk 1
        }
        bf16x8 ax = {0, 0, 0, 0, 0, 0, 0, 0};
        if (do0 && xlane) ax = *(const bf16x8*)&uS.xs[(t * BT + bx) * 8];

        f32x4 acc0[4], acc1[4];
        if (do0) {
            #pragma unroll
            for (int gi = 0; gi < 4; ++gi) acc0[gi] = __builtin_amdgcn_mfma_f32_16x16x32_bf16(a00, w0f[gi][0], kZ, 0, 0, 0);
            #pragma unroll
            for (int gi = 0; gi < 4; ++gi) acc0[gi] = __builtin_amdgcn_mfma_f32_16x16x32_bf16(a01, w0f[gi][1], acc0[gi], 0, 0, 0);
            #pragma unroll
            for (int gi = 0; gi < 4; ++gi) acc0[gi] = __builtin_amdgcn_mfma_f32_16x16x32_bf16(ax,  w0f[gi][2], acc0[gi], 0, 0, 0);
        }
        if (do1) {
            #pragma unroll
            for (int gi = 0; gi < 4; ++gi) acc1[gi] = __builtin_amdgcn_mfma_f32_16x16x32_bf16(a00, w1f[gi][0], kZ, 0, 0, 0);
            #pragma unroll
            for (int gi = 0; gi < 4; ++gi) acc1[gi] = __builtin_amdgcn_mfma_f32_16x16x32_bf16(a01, w1f[gi][1], acc1[gi], 0, 0, 0);
            #pragma unroll
            for (int gi = 0; gi < 4; ++gi) acc1[gi] = __builtin_amdgcn_mfma_f32_16x16x32_bf16(a12, w1f[gi][2], acc1[gi], 0, 0, 0);
            #pragma unroll
            for (int gi = 0; gi < 4; ++gi) acc1[gi] = __builtin_amdgcn_mfma_f32_16x16x32_bf16(a13, w1f[gi][3], acc1[gi], 0, 0, 0);
        }

        float h0v = 0.0f, h1v = 0.0f;
        if (do0) h0v = cellfuse(acc0[0][0], acc0[1][0], acc0[2][0], acc0[3][0], c0);
        if (do1) {
            h1v = cellfuse(acc1[0][0] + b1v[0], acc1[1][0] + b1v[1],
                           acc1[2][0] + b1v[2], acc1[3][0] + b1v[3], c1);
            h1fin = h1v;
        }
        unsigned pk = pk_bf16(h0v, h1v);
        if (do0) wb[(4 * g) * LDH + u]      = (ushort)pk;
        if (do1) wb[(4 * g) * LDH + 64 + u] = (ushort)(pk >> 16);
        __syncthreads();
    };

    #pragma unroll 1
    for (int t = 0; t < TSTEPS; t += 2) {
        body(t,     hreg[0], hreg[1]);
        body(t + 1, hreg[1], hreg[0]);
    }
    body(TSTEPS, hreg[0], hreg[1]);   // drain: layer1 step T-1

    // epilogue: FC on fp32 final h1
    uS.hfin[g * H + u] = h1fin;
    __syncthreads();
    if (tid < BT * 2) {
        const int b = tid >> 1, cls = tid & 1;
        float s = bfc[cls];
        for (int k = 0; k < H; ++k) s += uS.hfin[b * H + k] * Wfc[cls * H + k];
        out[(size_t)(bb + b) * 2 + cls] = s;
    }
}

extern "C" void kernel_launch(void* const* d_in, const int* in_sizes, int n_in,
                              void* d_out, int out_size, void* d_ws, size_t ws_size,
                              hipStream_t stream) {
    const float* x    = (const float*)d_in[0];
    const float* Wih0 = (const float*)d_in[1];
    const float* Whh0 = (const float*)d_in[2];
    const float* bih0 = (const float*)d_in[3];
    const float* bhh0 = (const float*)d_in[4];
    const float* Wih1 = (const float*)d_in[5];
    const float* Whh1 = (const float*)d_in[6];
    const float* bih1 = (const float*)d_in[7];
    const float* bhh1 = (const float*)d_in[8];
    const float* Wfc  = (const float*)d_in[9];
    const float* bfc  = (const float*)d_in[10];
    float* out = (float*)d_out;

    lstm2_kernel<<<NBLK, 256, 0, stream>>>(x, Wih0, Whh0, bih0, bhh0,
                                           Wih1, Whh1, bih1, bhh1, Wfc, bfc, out);
}

// Round 10
// 252.044 us; speedup vs baseline: 4.9466x; 1.2761x over previous
//
#include <hip/hip_runtime.h>
#include <hip/hip_bf16.h>

#define BATCH 4096
#define TSTEPS 256
#define NF 5
#define H 64
#define BT 8           // batch tile per block (sparse rows 0,1,4,5,8,9,12,13)
#define LDH 136        // hreg row stride in ushorts
#define NBLK (BATCH / BT)   // 512 blocks -> 2 blocks/CU -> 2 waves/SIMD

typedef __attribute__((ext_vector_type(8))) short bf16x8;
typedef __attribute__((ext_vector_type(4))) float f32x4;
typedef __attribute__((ext_vector_type(2))) float f32x2;

#define LOG2E 1.4426950408889634f
#define TWOLOG2E 2.8853900817779268f

__device__ __forceinline__ ushort f2bf(float f) {
    union { float f; unsigned u; } v; v.f = f;
    unsigned u = v.u;
    unsigned r = (u + 0x7FFFu + ((u >> 16) & 1u)) >> 16;  // RNE
    return (ushort)r;
}
__device__ __forceinline__ float bf2f(ushort s) {
    union { unsigned u; float f; } v; v.u = ((unsigned)s) << 16;
    return v.f;
}
__device__ __forceinline__ unsigned pk_bf16(float lo, float hi) {
    unsigned pk;
    asm("v_cvt_pk_bf16_f32 %0, %1, %2" : "=v"(pk) : "v"(lo), "v"(hi));
    return pk;
}

__global__ __launch_bounds__(256, 2)
void lstm2_kernel(const float* __restrict__ x,
                  const float* __restrict__ Wih0, const float* __restrict__ Whh0,
                  const float* __restrict__ bih0, const float* __restrict__ bhh0,
                  const float* __restrict__ Wih1, const float* __restrict__ Whh1,
                  const float* __restrict__ bih1, const float* __restrict__ bhh1,
                  const float* __restrict__ Wfc, const float* __restrict__ bfc,
                  float* __restrict__ out)
{
    __shared__ union {
        ushort xs[TSTEPS * BT * 8];   // bf16 x [t][b][8]; cols 5,6 = 1.0 (bias), 7 = 0
        float  hfin[BT * H];          // epilogue: fp32 final h1
    } uS;
    __shared__ ushort hreg[2][16 * LDH];  // dbuf state; cols 0..63 h0, 64..127 h1

    const int tid = threadIdx.x;
    const int w   = tid >> 6;
    const int l   = tid & 63;
    const int g   = l >> 4;
    const int lr  = l & 15;
    const int bb  = blockIdx.x * BT;

    // ---- stage x tile into LDS as bf16; pad cols 5,6 = 1.0 (bias cols) ----
    {
        const int b  = tid & 7;
        const int t0 = tid >> 3;
        const ushort one = f2bf(1.0f);
        for (int tt = t0; tt < TSTEPS; tt += 32) {
            const float* xp = x + ((size_t)(bb + b) * TSTEPS + tt) * NF;
            bf16x8 v;
            v[0] = (short)f2bf(xp[0]); v[1] = (short)f2bf(xp[1]);
            v[2] = (short)f2bf(xp[2]); v[3] = (short)f2bf(xp[3]);
            v[4] = (short)f2bf(xp[4]); v[5] = (short)one; v[6] = (short)one; v[7] = 0;
            *(bf16x8*)&uS.xs[(tt * BT + b) * 8] = v;
        }
    }
    for (int i = tid; i < 2 * 16 * LDH; i += 256) (&hreg[0][0])[i] = 0;

    // ---- weight fragments resident in VGPRs, gate-scaled for fused EW ----
    // gates i,f,o scaled +log2e; gate g scaled +2log2e.
    // wave w covers unit u = 16w+lr; gate gi at col n = 64*gi + u.
    // k-map (A and B): chunk c, group g, elem j -> k = 32c + 8g + j.
    const int u = 16 * w + lr;
    bf16x8 w0f[4][3], w1f[4][4];
    f32x4 b1acc[4];
    #pragma unroll
    for (int gi = 0; gi < 4; ++gi) {
        const float sc = (gi == 2) ? TWOLOG2E : LOG2E;
        const int n = 64 * gi + u;
        const float b0 = (bih0[n] + bhh0[n]) * sc;
        const float b1 = (bih1[n] + bhh1[n]) * sc;
        { f32x4 a = {b1, b1, b1, b1}; b1acc[gi] = a; }
        #pragma unroll
        for (int c = 0; c < 2; ++c) {
            const float* p = Whh0 + n * H + 32 * c + 8 * g;
            bf16x8 v;
            #pragma unroll
            for (int j = 0; j < 8; ++j) v[j] = (short)f2bf(p[j] * sc);
            w0f[gi][c] = v;
        }
        {
            const ushort bhi = f2bf(b0);
            const ushort blo = f2bf(b0 - bf2f(bhi));
            bf16x8 v;
            #pragma unroll
            for (int j = 0; j < 8; ++j) {
                int kk = 8 * g + j;
                ushort val = 0;
                if (kk < NF) val = f2bf(Wih0[n * NF + kk] * sc);
                else if (kk == 5) val = bhi;
                else if (kk == 6) val = blo;
                v[j] = (short)val;
            }
            w0f[gi][2] = v;
        }
        #pragma unroll
        for (int c = 0; c < 4; ++c) {
            const float* p = (c < 2) ? (Wih1 + n * H + 32 * c + 8 * g)
                                     : (Whh1 + n * H + 32 * (c - 2) + 8 * g);
            bf16x8 v;
            #pragma unroll
            for (int j = 0; j < 8; ++j) v[j] = (short)f2bf(p[j] * sc);
            w1f[gi][c] = v;
        }
    }

    // fused LSTM cell on a PAIR of cells (f32x2 -> v_pk_* f32 math):
    //   c' = [e_f (e_i+1)(E_g+1) c + (e_f+1) e_i (E_g-1)] / [(e_f+1)(e_i+1)(E_g+1)]
    //   h  = e_o (E_c-1) / [(e_o+1)(E_c+1)],  E_c = exp2(clamp(2c'·log2e, ±15))
    auto cellfuse2 = [&](f32x2 xi, f32x2 xf, f32x2 xg, f32x2 xo, f32x2& cst) -> f32x2 {
        f32x2 ei, ef, Eg, eo;
        ei.x = __builtin_amdgcn_exp2f(xi.x); ei.y = __builtin_amdgcn_exp2f(xi.y);
        ef.x = __builtin_amdgcn_exp2f(xf.x); ef.y = __builtin_amdgcn_exp2f(xf.y);
        Eg.x = __builtin_amdgcn_exp2f(xg.x); Eg.y = __builtin_amdgcn_exp2f(xg.y);
        eo.x = __builtin_amdgcn_exp2f(xo.x); eo.y = __builtin_amdgcn_exp2f(xo.y);
        f32x2 a1 = ei + 1.0f, a2 = ef + 1.0f, a3 = Eg + 1.0f, a4 = Eg - 1.0f;
        f32x2 P  = a1 * a3;
        f32x2 t1 = ef * cst;
        f32x2 t3 = (a2 * ei) * a4;
        f32x2 num; num.x = fmaf(t1.x, P.x, t3.x); num.y = fmaf(t1.y, P.y, t3.y);
        f32x2 den = P * a2;
        f32x2 R; R.x = __builtin_amdgcn_rcpf(den.x); R.y = __builtin_amdgcn_rcpf(den.y);
        f32x2 cn = num * R;
        cst = cn;
        f32x2 cs = cn * TWOLOG2E;
        f32x2 ct; ct.x = __builtin_amdgcn_fmed3f(cs.x, -15.0f, 15.0f);
                  ct.y = __builtin_amdgcn_fmed3f(cs.y, -15.0f, 15.0f);
        f32x2 Ec; Ec.x = __builtin_amdgcn_exp2f(ct.x); Ec.y = __builtin_amdgcn_exp2f(ct.y);
        f32x2 hn = eo * (Ec - 1.0f);
        f32x2 hd = (eo + 1.0f) * (Ec + 1.0f);
        f32x2 Rh; Rh.x = __builtin_amdgcn_rcpf(hd.x); Rh.y = __builtin_amdgcn_rcpf(hd.y);
        return hn * Rh;
    };

    f32x2 c0v = {0, 0}, c1v = {0, 0}, h1finv = {0, 0};
    const bool xlane = (g == 0) && ((lr & 2) == 0);
    const int  bx    = ((lr >> 2) << 1) | (lr & 1);

    __syncthreads();

    const int arow = lr * LDH;
    const f32x4 kZ = {0, 0, 0, 0};
    const bf16x8 kZ8 = {0, 0, 0, 0, 0, 0, 0, 0};
    const int wadr0 = (4 * g + 0) * LDH + u;
    const int wadr1 = (4 * g + 1) * LDH + u;

    // ---- STEADY body (t in [1,255]): single basic block, L0(t) + L1(t-1) ----
    auto bodyS = [&](int t, const ushort* __restrict__ rb, ushort* __restrict__ wb) {
        bf16x8 a00 = *(const bf16x8*)&rb[arow + 8 * g];
        bf16x8 a01 = *(const bf16x8*)&rb[arow + 32 + 8 * g];
        bf16x8 a12 = *(const bf16x8*)&rb[arow + 64 + 8 * g];
        bf16x8 a13 = *(const bf16x8*)&rb[arow + 96 + 8 * g];
        bf16x8 axv = *(const bf16x8*)&uS.xs[(t * BT + bx) * 8];
        bf16x8 ax  = xlane ? axv : kZ8;   // cndmask, no branch

        // L0: 2-chain (accA) || 1 independent (accB)
        f32x4 accA[4], accB[4];
        #pragma unroll
        for (int gi = 0; gi < 4; ++gi) accA[gi] = __builtin_amdgcn_mfma_f32_16x16x32_bf16(a00, w0f[gi][0], kZ, 0, 0, 0);
        #pragma unroll
        for (int gi = 0; gi < 4; ++gi) accB[gi] = __builtin_amdgcn_mfma_f32_16x16x32_bf16(ax,  w0f[gi][2], kZ, 0, 0, 0);
        #pragma unroll
        for (int gi = 0; gi < 4; ++gi) accA[gi] = __builtin_amdgcn_mfma_f32_16x16x32_bf16(a01, w0f[gi][1], accA[gi], 0, 0, 0);

        // L1: two independent 2-chains
        f32x4 accC[4], accD[4];
        #pragma unroll
        for (int gi = 0; gi < 4; ++gi) accC[gi] = __builtin_amdgcn_mfma_f32_16x16x32_bf16(a00, w1f[gi][0], b1acc[gi], 0, 0, 0);
        #pragma unroll
        for (int gi = 0; gi < 4; ++gi) accD[gi] = __builtin_amdgcn_mfma_f32_16x16x32_bf16(a12, w1f[gi][2], kZ, 0, 0, 0);
        #pragma unroll
        for (int gi = 0; gi < 4; ++gi) accC[gi] = __builtin_amdgcn_mfma_f32_16x16x32_bf16(a01, w1f[gi][1], accC[gi], 0, 0, 0);
        #pragma unroll
        for (int gi = 0; gi < 4; ++gi) accD[gi] = __builtin_amdgcn_mfma_f32_16x16x32_bf16(a13, w1f[gi][3], accD[gi], 0, 0, 0);

        // L0 EW (critical path) — L1 MFMAs above fill its stall slots
        f32x2 g0[4];
        #pragma unroll
        for (int gi = 0; gi < 4; ++gi) { g0[gi].x = accA[gi][0] + accB[gi][0]; g0[gi].y = accA[gi][1] + accB[gi][1]; }
        f32x2 h0p = cellfuse2(g0[0], g0[1], g0[2], g0[3], c0v);
        unsigned pk0 = pk_bf16(h0p.x, h0p.y);
        wb[wadr0] = (ushort)pk0;
        wb[wadr1] = (ushort)(pk0 >> 16);

        // L1 EW
        f32x2 g1[4];
        #pragma unroll
        for (int gi = 0; gi < 4; ++gi) { g1[gi].x = accC[gi][0] + accD[gi][0]; g1[gi].y = accC[gi][1] + accD[gi][1]; }
        f32x2 h1p = cellfuse2(g1[0], g1[1], g1[2], g1[3], c1v);
        h1finv = h1p;
        unsigned pk1 = pk_bf16(h1p.x, h1p.y);
        wb[wadr0 + 64] = (ushort)pk1;
        wb[wadr1 + 64] = (ushort)(pk1 >> 16);

        __syncthreads();
    };

    // ---- t = 0 peel: L0 only (h0(-1)=0), write h0(0) into hreg[1] ----
    {
        bf16x8 axv = *(const bf16x8*)&uS.xs[(0 * BT + bx) * 8];
        bf16x8 ax  = xlane ? axv : kZ8;
        f32x4 accB[4];
        #pragma unroll
        for (int gi = 0; gi < 4; ++gi) accB[gi] = __builtin_amdgcn_mfma_f32_16x16x32_bf16(ax, w0f[gi][2], kZ, 0, 0, 0);
        f32x2 g0[4];
        #pragma unroll
        for (int gi = 0; gi < 4; ++gi) { g0[gi].x = accB[gi][0]; g0[gi].y = accB[gi][1]; }
        f32x2 h0p = cellfuse2(g0[0], g0[1], g0[2], g0[3], c0v);
        unsigned pk0 = pk_bf16(h0p.x, h0p.y);
        hreg[1][wadr0] = (ushort)pk0;
        hreg[1][wadr1] = (ushort)(pk0 >> 16);
        __syncthreads();
    }

    // ---- steady loop t = 1..255 (odd t reads hreg[1]) ----
    #pragma unroll 1
    for (int t = 1; t <= 254; t += 2) {
        bodyS(t,     hreg[1], hreg[0]);
        bodyS(t + 1, hreg[0], hreg[1]);
    }
    bodyS(255, hreg[1], hreg[0]);

    // ---- t = 256 tail: L1 only from hreg[0] ----
    {
        const ushort* rb = hreg[0];
        bf16x8 a00 = *(const bf16x8*)&rb[arow + 8 * g];
        bf16x8 a01 = *(const bf16x8*)&rb[arow + 32 + 8 * g];
        bf16x8 a12 = *(const bf16x8*)&rb[arow + 64 + 8 * g];
        bf16x8 a13 = *(const bf16x8*)&rb[arow + 96 + 8 * g];
        f32x4 accC[4], accD[4];
        #pragma unroll
        for (int gi = 0; gi < 4; ++gi) accC[gi] = __builtin_amdgcn_mfma_f32_16x16x32_bf16(a00, w1f[gi][0], b1acc[gi], 0, 0, 0);
        #pragma unroll
        for (int gi = 0; gi < 4; ++gi) accD[gi] = __builtin_amdgcn_mfma_f32_16x16x32_bf16(a12, w1f[gi][2], kZ, 0, 0, 0);
        #pragma unroll
        for (int gi = 0; gi < 4; ++gi) accC[gi] = __builtin_amdgcn_mfma_f32_16x16x32_bf16(a01, w1f[gi][1], accC[gi], 0, 0, 0);
        #pragma unroll
        for (int gi = 0; gi < 4; ++gi) accD[gi] = __builtin_amdgcn_mfma_f32_16x16x32_bf16(a13, w1f[gi][3], accD[gi], 0, 0, 0);
        f32x2 g1[4];
        #pragma unroll
        for (int gi = 0; gi < 4; ++gi) { g1[gi].x = accC[gi][0] + accD[gi][0]; g1[gi].y = accC[gi][1] + accD[gi][1]; }
        h1finv = cellfuse2(g1[0], g1[1], g1[2], g1[3], c1v);
        __syncthreads();
    }

    // epilogue: FC on fp32 final h1
    uS.hfin[(2 * g + 0) * H + u] = h1finv.x;
    uS.hfin[(2 * g + 1) * H + u] = h1finv.y;
    __syncthreads();
    if (tid < BT * 2) {
        const int b = tid >> 1, cls = tid & 1;
        float s = bfc[cls];
        for (int k = 0; k < H; ++k) s += uS.hfin[b * H + k] * Wfc[cls * H + k];
        out[(size_t)(bb + b) * 2 + cls] = s;
    }
}

extern "C" void kernel_launch(void* const* d_in, const int* in_sizes, int n_in,
                              void* d_out, int out_size, void* d_ws, size_t ws_size,
                              hipStream_t stream) {
    const float* x    = (const float*)d_in[0];
    const float* Wih0 = (const float*)d_in[1];
    const float* Whh0 = (const float*)d_in[2];
    const float* bih0 = (const float*)d_in[3];
    const float* bhh0 = (const float*)d_in[4];
    const float* Wih1 = (const float*)d_in[5];
    const float* Whh1 = (const float*)d_in[6];
    const float* bih1 = (const float*)d_in[7];
    const float* bhh1 = (const float*)d_in[8];
    const float* Wfc  = (const float*)d_in[9];
    const float* bfc  = (const float*)d_in[10];
    float* out = (float*)d_out;

    lstm2_kernel<<<NBLK, 256, 0, stream>>>(x, Wih0, Whh0, bih0, bhh0,
                                           Wih1, Whh1, bih1, bhh1, Wfc, bfc, out);
}